// Round 1
// 400.231 us; speedup vs baseline: 1.0136x; 1.0136x over previous
//
#include <hip/hip_runtime.h>
#include <hip/hip_bf16.h>

// Problem constants
#define TDATA 100000
#define NE 500
#define NI 200
#define SUB 20
#define NB 3
#define TSYN 201

// Layout
#define SROW 100552              // 200 front pad + data + tail pad
#define HROW 216                 // conv taps padded: k in [-8,207] at [k+8]
#define STEPS_E 32               // K padded to 512 (31 full + 1 peel)
#define STEPS_I 13               // K padded to 208 (12 full + 1 peel)
#define NTILE 3125               // 100000 / 32 exactly, per matrix

// ws float offsets
#define OFF_HP  0                            // 2*20*216 = 8640 floats
#define OFF_BE  8640                         // e A-frags: 32*64*8 bf16 = 8192 float slots
#define OFF_BI  (OFF_BE + 8192)              // 16832; i A-frags: 13*64*8 bf16 = 3328 slots
#define OFF_INT (OFF_BI + 3328)              // 20160 (16B-aligned), inT = 40 rows x SROW

typedef __bf16 bf16x8 __attribute__((ext_vector_type(8)));
typedef float  f32x16 __attribute__((ext_vector_type(16)));

// ---------------------------------------------------------------------------
// Setup: conv taps | inT pad zeros | bf16 A-operand fragments (exact MFMA
// per-lane order: element j of lane l, k-step u  ->  C[s=l&31][k=16u+8*(l>>5)+j])
// Grid = 210*256 = 53760 exactly.  (unchanged from prior round)
// ---------------------------------------------------------------------------
__global__ __launch_bounds__(256) void setup_kernel(
    const float* __restrict__ C_e, const float* __restrict__ C_i,
    const float* __restrict__ K_syn, const float* __restrict__ tau_syn,
    const float* __restrict__ delta_syn, float* __restrict__ ws)
{
    int idx = blockIdx.x * 256 + threadIdx.x;
    if (idx < 8640) {                        // ---- conv taps (zero-padded)
        int c = idx / (SUB * HROW);
        int rem = idx - c * (SUB * HROW);
        int s = rem / HROW;
        int k = (rem - s * HROW) - 8;
        float v = 0.f;
        if (k >= 0 && k < TSYN) {
            float ts = (float)k - delta_syn[s * 2 + c];
            ts = ts < 0.f ? 0.f : ts;
            #pragma unroll
            for (int b = 0; b < NB; b++) {
                float tt = ts / expf(tau_syn[b * 2 + c]);
                v += K_syn[(s * NB + b) * 2 + c] * tt * expf(-tt);
            }
        }
        ws[OFF_HP + idx] = v;
    } else if (idx < 30720) {                // ---- inT front/tail pad zeros
        int j = idx - 8640;
        const int PERROW = 552;              // 200 front + 352 tail
        int row = j / PERROW;
        int e = j - row * PERROW;
        int off = (e < 200) ? e : (200 + TDATA + (e - 200));
        ws[OFF_INT + (long)row * SROW + off] = 0.f;
    } else if (idx < 47104) {                // ---- e A-frags (bf16)
        int j = idx - 30720;                 // 32*64*8 = 16384
        int step = j >> 9;
        int lane = (j >> 3) & 63;
        int jj = j & 7;
        int k = step * 16 + ((lane >> 5) << 3) + jj;
        int s = lane & 31;
        float v = (s < SUB && k < NE) ? C_e[s * NE + k] : 0.f;
        ((__hip_bfloat16*)(ws + OFF_BE))[j] = (__hip_bfloat16)v;
    } else {                                 // ---- i A-frags (bf16)
        int j = idx - 47104;                 // 13*64*8 = 6656
        int step = j >> 9;
        int lane = (j >> 3) & 63;
        int jj = j & 7;
        int k = step * 16 + ((lane >> 5) << 3) + jj;
        int s = lane & 31;
        float v = (s < SUB && k < NI) ? C_i[s * NI + k] : 0.f;
        ((__hip_bfloat16*)(ws + OFF_BI))[j] = (__hip_bfloat16)v;
    }
}

// ---------------------------------------------------------------------------
// MFMA GEMM v2: block = 32 consecutive rows = ONE contiguous 64KB (e) /
// 25.6KB (i) global region, staged to LDS via global_load_lds width=16
// (tid-linear => LDS holds packed row-major [32][K]; stride K=500 -> bank
// stride 20 mod 32 -> uniform 8 words/bank on ds_read_b128: conflict-free).
// 4 waves split K (u = wave, wave+4, ...), LDS-reduce partial accs, wave 0
// stores.  This replaces the old per-lane 16B @ 2000B-stride pattern (200k
// concurrent 64B streams -> HBM page thrash, 1.36 TB/s) with ~1 fat
// sequential stream per block.
// ---------------------------------------------------------------------------
template<int K, int STEPS>
__device__ __forceinline__ void gemm2_body(
    const float* __restrict__ S, const float* __restrict__ wsA,
    float* __restrict__ inT, float* tile, int blk, int tid)
{
    // ---- stage 32 packed rows (32*K floats, contiguous in S) ----
    const long gb = (long)blk * (32 * K);            // float index of tile base
    constexpr int TB = 32 * K * 4;                   // tile bytes
    {
        auto gsrc = (const __attribute__((address_space(1))) char*)(const void*)(S + gb);
        auto ldst = (__attribute__((address_space(3))) char*)(void*)tile;
        for (int off = tid * 16; off < TB; off += 4096)
            __builtin_amdgcn_global_load_lds(gsrc + off, ldst + off, 16, 0, 0);
    }
    asm volatile("s_waitcnt vmcnt(0)" ::: "memory");
    __syncthreads();

    // ---- compute: wave w does k-steps u = w, w+4, ... ----
    const int lane = tid & 63, wave = tid >> 6;
    const int n = lane & 31, h = lane >> 5;
    const float* rp = tile + n * K;
    const bf16x8* afr = (const bf16x8*)wsA;
    f32x16 acc = {};

    #pragma unroll 4
    for (int u = wave; u < STEPS; u += 4) {
        const int kb = u * 16 + h * 8;
        float4 lo = make_float4(0.f, 0.f, 0.f, 0.f);
        float4 hi = make_float4(0.f, 0.f, 0.f, 0.f);
        if (kb + 8 <= K) {                   // full 8 taps in-row
            lo = *(const float4*)(rp + kb);
            hi = *(const float4*)(rp + kb + 4);
        } else if (kb + 4 <= K) {            // peel: 4 taps (e: u=31,h=0)
            lo = *(const float4*)(rp + kb);
        }                                     // else: all-zero (A-frag zero too)
        bf16x8 b;
        b[0] = (__bf16)lo.x; b[1] = (__bf16)lo.y; b[2] = (__bf16)lo.z; b[3] = (__bf16)lo.w;
        b[4] = (__bf16)hi.x; b[5] = (__bf16)hi.y; b[6] = (__bf16)hi.z; b[7] = (__bf16)hi.w;
        bf16x8 a = afr[u * 64 + lane];
        acc = __builtin_amdgcn_mfma_f32_32x32x16_bf16(a, b, acc, 0, 0, 0);
    }

    // ---- cross-wave K-reduce through LDS (reuse tile; 12KB <= 25.6KB) ----
    __syncthreads();                          // all tile reads done
    if (wave != 0) {
        float4* dst = (float4*)(tile + ((wave - 1) * 64 + lane) * 16);
        dst[0] = make_float4(acc[0],  acc[1],  acc[2],  acc[3]);
        dst[1] = make_float4(acc[4],  acc[5],  acc[6],  acc[7]);
        dst[2] = make_float4(acc[8],  acc[9],  acc[10], acc[11]);
        dst[3] = make_float4(acc[12], acc[13], acc[14], acc[15]);
    }
    __syncthreads();
    if (wave == 0) {
        #pragma unroll
        for (int w = 0; w < 3; w++) {
            const float4* src = (const float4*)(tile + (w * 64 + lane) * 16);
            float4 p0 = src[0], p1 = src[1], p2 = src[2], p3 = src[3];
            acc[0]  += p0.x; acc[1]  += p0.y; acc[2]  += p0.z; acc[3]  += p0.w;
            acc[4]  += p1.x; acc[5]  += p1.y; acc[6]  += p1.z; acc[7]  += p1.w;
            acc[8]  += p2.x; acc[9]  += p2.y; acc[10] += p2.z; acc[11] += p2.w;
            acc[12] += p3.x; acc[13] += p3.y; acc[14] += p3.z; acc[15] += p3.w;
        }
        const long t = (long)blk * 32 + n;    // 32*3125 = 100000 exact, no guard
        #pragma unroll
        for (int r = 0; r < 16; r++) {
            int m = (r & 3) + 8 * (r >> 2) + 4 * h;
            if (m < SUB)
                inT[(long)m * SROW + 200 + t] = acc[r];
        }
    }
}

__global__ __launch_bounds__(256) void gemm_kernel(
    const float* __restrict__ Se, const float* __restrict__ Si,
    float* __restrict__ ws)
{
    __shared__ float tile[32 * NE];           // 64000 B; i-blocks use first 25.6KB
    const int tid = threadIdx.x;
    if (blockIdx.x < NTILE)
        gemm2_body<NE, STEPS_E>(Se, ws + OFF_BE, ws + OFF_INT,
                                tile, blockIdx.x, tid);
    else
        gemm2_body<NI, STEPS_I>(Si, ws + OFF_BI, ws + OFF_INT + (long)SUB * SROW,
                                tile, blockIdx.x - NTILE, tid);
}

// ---------------------------------------------------------------------------
// Conv: block = (s, 2048 t's); windows staged in LDS with i+(i>>5) swizzle
// (raw stride-8 lane pattern would be 16-way bank-conflicted); taps in LDS,
// broadcast ds_read_b128. Thread = 8 consecutive t's; 16-float reg window
// per 8-tap group -> 64 fmac per 16 LDS b32 reads. No s_load in loop.
// (unchanged from prior round)
// ---------------------------------------------------------------------------
#define SW(i) ((i) + ((i) >> 5))

__global__ __launch_bounds__(256) void conv_kernel(
    const float* __restrict__ ws, float* __restrict__ out)
{
    __shared__ __align__(16) float W[2][2336];   // SW(2255)=2325 max
    __shared__ __align__(16) float HT[2][208];
    const int tid = threadIdx.x;
    const int s = blockIdx.y;
    const long t0 = (long)blockIdx.x * 2048;

    // stage windows: W[c][q] = row_c[t0 - 208 + q], q in [0,2256)
    for (int i = tid; i < 1128; i += 256) {
        int c = i >= 564;
        int i4 = i - c * 564;
        float4 v = *(const float4*)(ws + OFF_INT + (long)(c * SUB + s) * SROW
                                    + t0 - 8 + 4 * i4);
        int b = 4 * i4;
        int p = SW(b);                        // contiguous within aligned-4 runs
        W[c][p] = v.x; W[c][p + 1] = v.y; W[c][p + 2] = v.z; W[c][p + 3] = v.w;
    }
    if (tid < 104) {                          // taps: 2 channels x 208
        int c = tid >= 52;
        int j4 = (tid - c * 52) * 4;
        *(float4*)&HT[c][j4] =
            *(const float4*)(ws + OFF_HP + (c * SUB + s) * HROW + 8 + j4);
    }
    __syncthreads();

    float acc[8];
    #pragma unroll
    for (int r = 0; r < 8; r++) acc[r] = 0.f;

    #pragma unroll
    for (int c = 0; c < 2; c++) {
        #pragma unroll 2
        for (int g = 0; g < 26; g++) {
            int k0 = g << 3;
            int xb = (tid << 3) + 200 - k0;
            float x[16];
            #pragma unroll
            for (int q = 0; q < 16; q++) x[q] = W[c][SW(xb + q)];
            float h[8];
            *(float4*)&h[0] = *(const float4*)&HT[c][k0];
            *(float4*)&h[4] = *(const float4*)&HT[c][k0 + 4];
            #pragma unroll
            for (int j = 0; j < 8; j++)
                #pragma unroll
                for (int r = 0; r < 8; r++)
                    acc[r] += h[j] * x[8 + r - j];
        }
    }

    #pragma unroll
    for (int r = 0; r < 8; r++) {
        long t = t0 + 8 * tid + r;
        if (t < TDATA) out[t * SUB + s] = acc[r];
    }
}

// ---------------------------------------------------------------------------
extern "C" void kernel_launch(void* const* d_in, const int* in_sizes, int n_in,
                              void* d_out, int out_size, void* d_ws, size_t ws_size,
                              hipStream_t stream)
{
    const float* S_e     = (const float*)d_in[0];
    const float* S_i     = (const float*)d_in[1];
    const float* C_e     = (const float*)d_in[2];
    const float* C_i     = (const float*)d_in[3];
    const float* K_syn   = (const float*)d_in[4];
    const float* tau_syn = (const float*)d_in[5];
    const float* delta   = (const float*)d_in[6];
    float* out = (float*)d_out;
    float* ws  = (float*)d_ws;

    hipLaunchKernelGGL(setup_kernel, dim3(210), dim3(256), 0, stream,
                       C_e, C_i, K_syn, tau_syn, delta, ws);
    hipLaunchKernelGGL(gemm_kernel, dim3(2 * NTILE), dim3(256), 0, stream,
                       S_e, S_i, ws);
    hipLaunchKernelGGL(conv_kernel, dim3(49, SUB), dim3(256), 0, stream,
                       ws, out);
}